// Round 7
// baseline (731.572 us; speedup 1.0000x reference)
//
#include <hip/hip_runtime.h>
#include <hip/hip_fp16.h>
#include <math.h>

#define NN   50000
#define EE   800000
#define IND  128
#define EDD  16
#define HIDD 32
#define NH   4
#define HC   128     // NH*HIDD
#define OUTD 64
#define NEG  0.1f
#define BN_EPS 1e-5f
#define LOG2E 1.44269504088896340736f

typedef __attribute__((ext_vector_type(2))) float v2f;

__device__ __forceinline__ float lrelu(float x) { return fmaxf(x, NEG * x); }
__device__ __forceinline__ v2f lrelu2(v2f v) { return __builtin_elementwise_max(v, v * NEG); }

struct Edge { v2f x, ea; };

// ---------------- prep: count (blocks [0,3125)) + embed+lin0 (blocks [3125,9375)) ----
__global__ void prep_kernel(const int* __restrict__ ei, int* __restrict__ cnt,
                            const float* __restrict__ x,
                            const float* __restrict__ W0, const float* __restrict__ b0,
                            const float* __restrict__ g, const float* __restrict__ bb,
                            const float* __restrict__ bm, const float* __restrict__ bv,
                            const float* __restrict__ Wl, const float* __restrict__ bl,
                            const float* __restrict__ Wr, const float* __restrict__ br,
                            __half2* __restrict__ xl, float* __restrict__ xr) {
    if (blockIdx.x < EE / 256) {
        int e = blockIdx.x * 256 + threadIdx.x;
        atomicAdd(&cnt[ei[EE + e]], 1);
        return;
    }
    int blk = blockIdx.x - EE / 256;
    int tid = threadIdx.x;
    int n0 = blk * 8;
    __shared__ float sx[8 * IND];
    __shared__ float se[8][HIDD];
    // load 8 rows of x (1024 floats): float4 per thread, coalesced
    *(float4*)(sx + tid * 4) = *(const float4*)(x + (size_t)n0 * IND + tid * 4);
    __syncthreads();
    {   // embed: node r = tid>>5, channel c = tid&31
        int r = tid >> 5, c = tid & 31;
        float acc = b0[c];
        const float* wr = W0 + c * IND;
        const float* xrow = sx + r * IND;
        #pragma unroll 8
        for (int k = 0; k < IND; k++) acc += xrow[k] * wr[k];
        float bn = (acc - bm[c]) * (1.0f / sqrtf(bv[c] + BN_EPS)) * g[c] + bb[c];
        se[r][c] = lrelu(bn);
    }
    __syncthreads();
    // lin0: mat = tid>>7 (0:xl fp16, 1:xr fp32); grp = (tid>>6)&1 (4-node group);
    // pr = tid&63 -> channel pair c0 = 2*pr
    int mat = tid >> 7, grp = (tid >> 6) & 1, pr = tid & 63;
    int c0 = 2 * pr;
    const float* W = mat ? Wr : Wl;
    const float* b = mat ? br : bl;
    v2f bv2 = (v2f){b[c0], b[c0 + 1]};
    v2f a0 = bv2, a1 = bv2, a2 = bv2, a3 = bv2;
    const float* w0 = W + c0 * HIDD;
    const float* w1 = w0 + HIDD;
    int nb = grp * 4;
    #pragma unroll
    for (int k = 0; k < HIDD; k++) {
        v2f wk = (v2f){w0[k], w1[k]};
        a0 += wk * se[nb + 0][k]; a1 += wk * se[nb + 1][k];
        a2 += wk * se[nb + 2][k]; a3 += wk * se[nb + 3][k];
    }
    if (mat == 0) {
        xl[((unsigned)(n0 + nb + 0) << 6) + pr] = __floats2half2_rn(a0.x, a0.y);
        xl[((unsigned)(n0 + nb + 1) << 6) + pr] = __floats2half2_rn(a1.x, a1.y);
        xl[((unsigned)(n0 + nb + 2) << 6) + pr] = __floats2half2_rn(a2.x, a2.y);
        xl[((unsigned)(n0 + nb + 3) << 6) + pr] = __floats2half2_rn(a3.x, a3.y);
    } else {
        *(float2*)(xr + ((unsigned)(n0 + nb + 0) << 7) + c0) = make_float2(a0.x, a0.y);
        *(float2*)(xr + ((unsigned)(n0 + nb + 1) << 7) + c0) = make_float2(a1.x, a1.y);
        *(float2*)(xr + ((unsigned)(n0 + nb + 2) << 7) + c0) = make_float2(a2.x, a2.y);
        *(float2*)(xr + ((unsigned)(n0 + nb + 3) << 7) + c0) = make_float2(a3.x, a3.y);
    }
}

// parallel exclusive scan of cnt[NN] -> rowstart[NN+1]
__global__ void scan1_kernel(const int* cnt, int* pre, int* bsum) {
    int i = blockIdx.x * 1024 + threadIdx.x;
    int lane = threadIdx.x & 63, wid = threadIdx.x >> 6;
    __shared__ int wsum[16];
    int v = (i < NN) ? cnt[i] : 0;
    int s = v;
    #pragma unroll
    for (int off = 1; off < 64; off <<= 1) {
        int t = __shfl_up(s, off);
        if (lane >= off) s += t;
    }
    if (lane == 63) wsum[wid] = s;
    __syncthreads();
    if (wid == 0) {
        int ws = (lane < 16) ? wsum[lane] : 0;
        #pragma unroll
        for (int off = 1; off < 16; off <<= 1) {
            int t = __shfl_up(ws, off);
            if (lane >= off) ws += t;
        }
        if (lane < 16) wsum[lane] = ws;
    }
    __syncthreads();
    int woff = (wid > 0) ? wsum[wid - 1] : 0;
    if (i < NN) pre[i] = woff + s - v;
    if (threadIdx.x == 1023) bsum[blockIdx.x] = wsum[15];
}

__global__ void scan3_kernel(int* rowstart, const int* pre, const int* bsum, int nb) {
    __shared__ int boff_s;
    if (threadIdx.x < 64) {
        int lane = threadIdx.x;
        int v = (lane < nb) ? bsum[lane] : 0;
        int s = v;
        #pragma unroll
        for (int off = 1; off < 64; off <<= 1) {
            int t = __shfl_up(s, off);
            if (lane >= off) s += t;
        }
        if (lane == (int)blockIdx.x) boff_s = s - v;
    }
    __syncthreads();
    int i = blockIdx.x * 1024 + threadIdx.x;
    if (i < NN) rowstart[i] = pre[i] + boff_s;
    if (i == 0) rowstart[NN] = EE;
}

__global__ void scatter_kernel(const int* ei, const int* rowstart, int* cursor, int2* csr_es) {
    int e = blockIdx.x * blockDim.x + threadIdx.x;
    if (e >= EE) return;
    int d = ei[EE + e];
    int pos = rowstart[d] + atomicAdd(&cursor[d], 1);
    csr_es[pos] = make_int2(e, ei[e]);
}

// ---------------- per-layer linear: h1 -> xl (fp16), xr (fp32); 8 nodes/block ------
__global__ void lin_kernel(const float* __restrict__ f,
                           const float* __restrict__ Wl, const float* __restrict__ bl,
                           const float* __restrict__ Wr, const float* __restrict__ br,
                           __half2* __restrict__ xl, float* __restrict__ xr) {
    int tid = threadIdx.x;
    int n0 = blockIdx.x * 8;
    __shared__ float se[8][HIDD];
    se[tid >> 5][tid & 31] = f[((unsigned)(n0 + (tid >> 5)) << 5) + (tid & 31)];
    __syncthreads();
    int mat = tid >> 7, grp = (tid >> 6) & 1, pr = tid & 63;
    int c0 = 2 * pr;
    const float* W = mat ? Wr : Wl;
    const float* b = mat ? br : bl;
    v2f bv2 = (v2f){b[c0], b[c0 + 1]};
    v2f a0 = bv2, a1 = bv2, a2 = bv2, a3 = bv2;
    const float* w0 = W + c0 * HIDD;
    const float* w1 = w0 + HIDD;
    int nb = grp * 4;
    #pragma unroll
    for (int k = 0; k < HIDD; k++) {
        v2f wk = (v2f){w0[k], w1[k]};
        a0 += wk * se[nb + 0][k]; a1 += wk * se[nb + 1][k];
        a2 += wk * se[nb + 2][k]; a3 += wk * se[nb + 3][k];
    }
    if (mat == 0) {
        xl[((unsigned)(n0 + nb + 0) << 6) + pr] = __floats2half2_rn(a0.x, a0.y);
        xl[((unsigned)(n0 + nb + 1) << 6) + pr] = __floats2half2_rn(a1.x, a1.y);
        xl[((unsigned)(n0 + nb + 2) << 6) + pr] = __floats2half2_rn(a2.x, a2.y);
        xl[((unsigned)(n0 + nb + 3) << 6) + pr] = __floats2half2_rn(a3.x, a3.y);
    } else {
        *(float2*)(xr + ((unsigned)(n0 + nb + 0) << 7) + c0) = make_float2(a0.x, a0.y);
        *(float2*)(xr + ((unsigned)(n0 + nb + 1) << 7) + c0) = make_float2(a1.x, a1.y);
        *(float2*)(xr + ((unsigned)(n0 + nb + 2) << 7) + c0) = make_float2(a2.x, a2.y);
        *(float2*)(xr + ((unsigned)(n0 + nb + 3) << 7) + c0) = make_float2(a3.x, a3.y);
    }
}

// ---------------- fused: edge scoring + softmax + aggregate + self-loop -------------
// one wave per dst node; lane owns channels (2*lane, 2*lane+1); head = lane>>4
// Logits are O(1) by construction -> plain exp2 softmax (shift-invariant, exact).
template<bool OUTHEAD>
__global__ void gat_fused_kernel(const __half2* __restrict__ xl, const float* __restrict__ xr,
                                 const float* __restrict__ eattr,
                                 const float* __restrict__ We, const float* __restrict__ att,
                                 const int* __restrict__ rowstart, const int2* __restrict__ csr_es,
                                 const float* __restrict__ bias,
                                 const float* __restrict__ Wout, const float* __restrict__ bout,
                                 float* __restrict__ out) {
    int n = (blockIdx.x * blockDim.x + threadIdx.x) >> 6;
    int lane = threadIdx.x & 63;
    if (n >= NN) return;
    n = __builtin_amdgcn_readfirstlane(n);
    int start = __builtin_amdgcn_readfirstlane(rowstart[n]);
    int end   = __builtin_amdgcn_readfirstlane(rowstart[n + 1]);
    int deg = end - start;
    int c0 = 2 * lane;

    v2f xrv = *(const v2f*)(xr + ((unsigned)n << 7) + c0);
    v2f attv = *(const v2f*)(att + c0) * LOG2E;     // fold log2e: exp(p)=exp2(p*log2e)
    v2f wv[16];
    {
        const float* ra = We + c0 * EDD;
        const float* rb = ra + EDD;
        float4 a0 = *(const float4*)(ra),     a1 = *(const float4*)(ra + 4);
        float4 a2 = *(const float4*)(ra + 8), a3 = *(const float4*)(ra + 12);
        float4 b0 = *(const float4*)(rb),     b1 = *(const float4*)(rb + 4);
        float4 b2 = *(const float4*)(rb + 8), b3 = *(const float4*)(rb + 12);
        wv[0]=(v2f){a0.x,b0.x}; wv[1]=(v2f){a0.y,b0.y}; wv[2]=(v2f){a0.z,b0.z}; wv[3]=(v2f){a0.w,b0.w};
        wv[4]=(v2f){a1.x,b1.x}; wv[5]=(v2f){a1.y,b1.y}; wv[6]=(v2f){a1.z,b1.z}; wv[7]=(v2f){a1.w,b1.w};
        wv[8]=(v2f){a2.x,b2.x}; wv[9]=(v2f){a2.y,b2.y}; wv[10]=(v2f){a2.z,b2.z}; wv[11]=(v2f){a2.w,b2.w};
        wv[12]=(v2f){a3.x,b3.x}; wv[13]=(v2f){a3.y,b3.y}; wv[14]=(v2f){a3.z,b3.z}; wv[15]=(v2f){a3.w,b3.w};
    }

    float lh = 0.f;
    v2f acc   = (v2f){0.f, 0.f};
    v2f easum = (v2f){0.f, 0.f};

    auto load_edge = [&](int i) -> Edge {
        int2 es = csr_es[i];
        int s = __builtin_amdgcn_readfirstlane(es.y);
        int e = __builtin_amdgcn_readfirstlane(es.x);
        Edge r;
        float2 xf = __half22float2(xl[((unsigned)s << 6) + lane]);
        r.x = (v2f){xf.x, xf.y};
        const float4* ep = (const float4*)(eattr + ((size_t)(unsigned)e << 4));
        float4 q0 = ep[0], q1 = ep[1], q2 = ep[2], q3 = ep[3];
        r.ea = wv[0]*q0.x + wv[1]*q0.y + wv[2]*q0.z  + wv[3]*q0.w
             + wv[4]*q1.x + wv[5]*q1.y + wv[6]*q1.z  + wv[7]*q1.w
             + wv[8]*q2.x + wv[9]*q2.y + wv[10]*q2.z + wv[11]*q2.w
             + wv[12]*q3.x+ wv[13]*q3.y+ wv[14]*q3.z + wv[15]*q3.w;
        return r;
    };

    auto proc_edge = [&](const Edge& E) {
        easum += E.ea;
        v2f z  = E.x + xrv + E.ea;
        v2f mm = lrelu2(z);
        v2f pp = mm * attv;
        float p = pp.x + pp.y;
        p += __shfl_xor(p, 1); p += __shfl_xor(p, 2);
        p += __shfl_xor(p, 4); p += __shfl_xor(p, 8);   // per-head logit (log2 units)
        float w = exp2f(p);
        lh  += w;
        acc += E.x * w;
    };

    int i = start;
    int nfull = deg >> 2;
    if (nfull > 0) {
        Edge A0 = load_edge(i), A1 = load_edge(i + 1), A2 = load_edge(i + 2), A3 = load_edge(i + 3);
        for (int c = 1; c < nfull; c++) {
            Edge B0 = load_edge(i + 4), B1 = load_edge(i + 5),
                 B2 = load_edge(i + 6), B3 = load_edge(i + 7);
            proc_edge(A0); proc_edge(A1); proc_edge(A2); proc_edge(A3);
            A0 = B0; A1 = B1; A2 = B2; A3 = B3;
            i += 4;
        }
        proc_edge(A0); proc_edge(A1); proc_edge(A2); proc_edge(A3);
        i += 4;
    }
    // pipelined tail (<=3 edges): issue all loads, then process
    int rem = end - i;
    if (rem > 0) {
        Edge T0 = load_edge(i), T1, T2;
        T1.x = T1.ea = T2.x = T2.ea = (v2f){0.f, 0.f};
        if (rem > 1) T1 = load_edge(i + 1);
        if (rem > 2) T2 = load_edge(i + 2);
        proc_edge(T0);
        if (rem > 1) proc_edge(T1);
        if (rem > 2) proc_edge(T2);
    }

    // self-loop: We @ mean(eattr) == mean(We @ eattr); src = n
    {
        float invdeg = 1.0f / (float)(deg > 0 ? deg : 1);
        Edge L;
        float2 xf = __half22float2(xl[((unsigned)n << 6) + lane]);
        L.x = (v2f){xf.x, xf.y};
        L.ea = easum * invdeg;
        proc_edge(L);
    }

    float inv = 1.0f / lh;
    float acc0 = acc.x * inv, acc1 = acc.y * inv;
    acc0 += __shfl_xor(acc0, 16); acc0 += __shfl_xor(acc0, 32);
    acc1 += __shfl_xor(acc1, 16); acc1 += __shfl_xor(acc1, 32);

    if (!OUTHEAD) {
        if (lane < 16) {
            float2 o = make_float2(acc0 * 0.25f + bias[2 * lane],
                                   acc1 * 0.25f + bias[2 * lane + 1]);
            *(float2*)(out + ((unsigned)n << 5) + 2 * lane) = o;
        }
    } else {
        __shared__ float sh[4][HIDD];
        int w = threadIdx.x >> 6;
        if (lane < 16) {
            sh[w][2 * lane]     = acc0 * 0.25f + bias[2 * lane];
            sh[w][2 * lane + 1] = acc1 * 0.25f + bias[2 * lane + 1];
        }
        float a = bout[lane];
        const float* wr = Wout + lane * HIDD;
        #pragma unroll
        for (int k = 0; k < HIDD; k++) a += sh[w][k] * wr[k];
        out[((unsigned)n << 6) + lane] = lrelu(a);
    }
}

extern "C" void kernel_launch(void* const* d_in, const int* in_sizes, int n_in,
                              void* d_out, int out_size, void* d_ws, size_t ws_size,
                              hipStream_t stream) {
    const float* x     = (const float*)d_in[0];
    const int*   ei    = (const int*)  d_in[1];
    const float* eattr = (const float*)d_in[2];
    const float* W0    = (const float*)d_in[3];
    const float* b0    = (const float*)d_in[4];
    const float* bn_g  = (const float*)d_in[5];
    const float* bn_b  = (const float*)d_in[6];
    const float* bn_m  = (const float*)d_in[7];
    const float* bn_v  = (const float*)d_in[8];
    const float* Wl[2]   = { (const float*)d_in[9],  (const float*)d_in[16] };
    const float* bl[2]   = { (const float*)d_in[10], (const float*)d_in[17] };
    const float* Wr[2]   = { (const float*)d_in[11], (const float*)d_in[18] };
    const float* br[2]   = { (const float*)d_in[12], (const float*)d_in[19] };
    const float* We[2]   = { (const float*)d_in[13], (const float*)d_in[20] };
    const float* att[2]  = { (const float*)d_in[14], (const float*)d_in[21] };
    const float* bias[2] = { (const float*)d_in[15], (const float*)d_in[22] };
    const float* Wout  = (const float*)d_in[23];
    const float* bout  = (const float*)d_in[24];
    float* out = (float*)d_out;

    const int NB = (NN + 1023) / 1024;   // 49 scan blocks
    char* p = (char*)d_ws;
    auto carve = [&](size_t bytes) { char* r = p; p += (bytes + 255) & ~(size_t)255; return r; };
    float*   h1       = (float*)  carve((size_t)NN * HIDD * 4);   // layer1 out
    __half2* xl       = (__half2*)carve((size_t)NN * HC * 2);     // fp16 source-transform
    float*   xr       = (float*)  carve((size_t)NN * HC * 4);
    int*     cnt      = (int*)    carve((size_t)2 * NN * 4);      // cnt + cursor contiguous
    int*     cursor   = cnt + NN;
    int*     pre      = (int*)    carve((size_t)NN * 4);
    int*     bsum     = (int*)    carve((size_t)64 * 4);
    int*     rowstart = (int*)    carve((size_t)(NN + 1) * 4);
    int2*    csr_es   = (int2*)   carve((size_t)EE * 8);

    hipMemsetAsync(cnt, 0, (size_t)2 * NN * 4, stream);

    // count (3125 blocks) + embed+lin0 (6250 blocks) in one launch
    prep_kernel<<<EE / 256 + NN / 8, 256, 0, stream>>>(
        ei, cnt, x, W0, b0, bn_g, bn_b, bn_m, bn_v, Wl[0], bl[0], Wr[0], br[0], xl, xr);
    scan1_kernel<<<NB, 1024, 0, stream>>>(cnt, pre, bsum);
    scan3_kernel<<<NB, 1024, 0, stream>>>(rowstart, pre, bsum, NB);
    scatter_kernel<<<(EE + 255) / 256, 256, 0, stream>>>(ei, rowstart, cursor, csr_es);

    gat_fused_kernel<false><<<(NN * 64) / 256, 256, 0, stream>>>(
        xl, xr, eattr, We[0], att[0], rowstart, csr_es, bias[0], nullptr, nullptr, h1);

    lin_kernel<<<NN / 8, 256, 0, stream>>>(h1, Wl[1], bl[1], Wr[1], br[1], xl, xr);
    gat_fused_kernel<true><<<(NN * 64) / 256, 256, 0, stream>>>(
        xl, xr, eattr, We[1], att[1], rowstart, csr_es, bias[1], Wout, bout, out);
}

// Round 8
// 601.135 us; speedup vs baseline: 1.2170x; 1.2170x over previous
//
#include <hip/hip_runtime.h>
#include <hip/hip_fp16.h>
#include <math.h>

#define NN   50000
#define EE   800000
#define IND  128
#define EDD  16
#define HIDD 32
#define NH   4
#define HC   128     // NH*HIDD
#define OUTD 64
#define NEG  0.1f
#define BN_EPS 1e-5f
#define LOG2E 1.44269504088896340736f

typedef __attribute__((ext_vector_type(2))) float v2f;

__device__ __forceinline__ float lrelu(float x) { return fmaxf(x, NEG * x); }
__device__ __forceinline__ v2f lrelu2(v2f v) { return __builtin_elementwise_max(v, v * NEG); }

struct Edge { v2f x, ea; };

// ---------------- count (+rank) and weight fold/transpose in one grid -------------
// blocks [0, EE/256): rank[e] = atomicAdd(cnt[dst], 1)
// block EE/256: fold BN into W0 -> W0fT[k][c]; transpose Wl/Wr (both layers)
__global__ void count_fold_kernel(const int* __restrict__ ei, int* __restrict__ cnt,
                                  int* __restrict__ rank,
                                  const float* __restrict__ W0, const float* __restrict__ b0,
                                  const float* __restrict__ g, const float* __restrict__ bb,
                                  const float* __restrict__ bm, const float* __restrict__ bv,
                                  const float* __restrict__ Wl0, const float* __restrict__ Wr0,
                                  const float* __restrict__ Wl1, const float* __restrict__ Wr1,
                                  float* __restrict__ w0t, float* __restrict__ b0f,
                                  float* __restrict__ wlt0, float* __restrict__ wrt0,
                                  float* __restrict__ wlt1, float* __restrict__ wrt1) {
    if (blockIdx.x < EE / 256) {
        int e = blockIdx.x * 256 + threadIdx.x;
        rank[e] = atomicAdd(&cnt[ei[EE + e]], 1);
        return;
    }
    int tid = threadIdx.x;
    // W0fT[k][c] = W0[c][k] * g[c] / sqrt(v[c]+eps)   (IND x HIDD)
    for (int idx = tid; idx < IND * HIDD; idx += 256) {
        int k = idx >> 5, c = idx & 31;
        float s = g[c] * (1.0f / sqrtf(bv[c] + BN_EPS));
        w0t[idx] = W0[c * IND + k] * s;
    }
    if (tid < HIDD) {
        float s = g[tid] * (1.0f / sqrtf(bv[tid] + BN_EPS));
        b0f[tid] = (b0[tid] - bm[tid]) * s + bb[tid];
    }
    // WT[k][c] = W[c][k]   (HIDD x HC)
    for (int idx = tid; idx < HIDD * HC; idx += 256) {
        int k = idx >> 7, c = idx & 127;
        wlt0[idx] = Wl0[c * HIDD + k];
        wrt0[idx] = Wr0[c * HIDD + k];
        wlt1[idx] = Wl1[c * HIDD + k];
        wrt1[idx] = Wr1[c * HIDD + k];
    }
}

// parallel exclusive scan of cnt[NN] -> rowstart[NN+1]
__global__ void scan1_kernel(const int* cnt, int* pre, int* bsum) {
    int i = blockIdx.x * 1024 + threadIdx.x;
    int lane = threadIdx.x & 63, wid = threadIdx.x >> 6;
    __shared__ int wsum[16];
    int v = (i < NN) ? cnt[i] : 0;
    int s = v;
    #pragma unroll
    for (int off = 1; off < 64; off <<= 1) {
        int t = __shfl_up(s, off);
        if (lane >= off) s += t;
    }
    if (lane == 63) wsum[wid] = s;
    __syncthreads();
    if (wid == 0) {
        int ws = (lane < 16) ? wsum[lane] : 0;
        #pragma unroll
        for (int off = 1; off < 16; off <<= 1) {
            int t = __shfl_up(ws, off);
            if (lane >= off) ws += t;
        }
        if (lane < 16) wsum[lane] = ws;
    }
    __syncthreads();
    int woff = (wid > 0) ? wsum[wid - 1] : 0;
    if (i < NN) pre[i] = woff + s - v;
    if (threadIdx.x == 1023) bsum[blockIdx.x] = wsum[15];
}

__global__ void scan3_kernel(int* rowstart, const int* pre, const int* bsum, int nb) {
    __shared__ int boff_s;
    if (threadIdx.x < 64) {
        int lane = threadIdx.x;
        int v = (lane < nb) ? bsum[lane] : 0;
        int s = v;
        #pragma unroll
        for (int off = 1; off < 64; off <<= 1) {
            int t = __shfl_up(s, off);
            if (lane >= off) s += t;
        }
        if (lane == (int)blockIdx.x) boff_s = s - v;
    }
    __syncthreads();
    int i = blockIdx.x * 1024 + threadIdx.x;
    if (i < NN) rowstart[i] = pre[i] + boff_s;
    if (i == 0) rowstart[NN] = EE;
}

// atomic-free scatter: position = rowstart[dst] + rank[e]
__global__ void scatter_kernel(const int* __restrict__ ei, const int* __restrict__ rowstart,
                               const int* __restrict__ rank, int2* __restrict__ csr_es) {
    int e = blockIdx.x * blockDim.x + threadIdx.x;
    if (e >= EE) return;
    int d = ei[EE + e];
    int pos = rowstart[d] + rank[e];
    csr_es[pos] = make_int2(e, ei[e]);
}

// ---------------- fused embed + layer-0 linear: x -> xl (fp16), xr (fp32) ----------
__global__ void embed_lin_kernel(const float* __restrict__ x,
                                 const float* __restrict__ w0t, const float* __restrict__ b0f,
                                 const float* __restrict__ wlt, const float* __restrict__ bl,
                                 const float* __restrict__ wrt, const float* __restrict__ br,
                                 __half2* __restrict__ xl, float* __restrict__ xr) {
    int tid = threadIdx.x;
    int n0 = blockIdx.x * 8;
    __shared__ float sx[8 * IND];
    __shared__ float se[8][HIDD];
    *(float4*)(sx + tid * 4) = *(const float4*)(x + (size_t)n0 * IND + tid * 4);
    __syncthreads();
    {   // embed: node r, channel c; weight read coalesced via transposed layout
        int r = tid >> 5, c = tid & 31;
        float acc = b0f[c];
        const float* xrow = sx + r * IND;
        #pragma unroll 8
        for (int k = 0; k < IND; k++) acc += xrow[k] * w0t[k * HIDD + c];
        se[r][c] = lrelu(acc);
    }
    __syncthreads();
    int mat = tid >> 7, grp = (tid >> 6) & 1, pr = tid & 63;
    int c0 = 2 * pr;
    const float* WT = mat ? wrt : wlt;
    const float* b  = mat ? br : bl;
    v2f bv2 = (v2f){b[c0], b[c0 + 1]};
    v2f a0 = bv2, a1 = bv2, a2 = bv2, a3 = bv2;
    int nb = grp * 4;
    #pragma unroll
    for (int k = 0; k < HIDD; k++) {
        v2f wk = *(const v2f*)(WT + k * HC + c0);   // coalesced across lanes
        a0 += wk * se[nb + 0][k]; a1 += wk * se[nb + 1][k];
        a2 += wk * se[nb + 2][k]; a3 += wk * se[nb + 3][k];
    }
    if (mat == 0) {
        xl[((unsigned)(n0 + nb + 0) << 6) + pr] = __floats2half2_rn(a0.x, a0.y);
        xl[((unsigned)(n0 + nb + 1) << 6) + pr] = __floats2half2_rn(a1.x, a1.y);
        xl[((unsigned)(n0 + nb + 2) << 6) + pr] = __floats2half2_rn(a2.x, a2.y);
        xl[((unsigned)(n0 + nb + 3) << 6) + pr] = __floats2half2_rn(a3.x, a3.y);
    } else {
        *(float2*)(xr + ((unsigned)(n0 + nb + 0) << 7) + c0) = make_float2(a0.x, a0.y);
        *(float2*)(xr + ((unsigned)(n0 + nb + 1) << 7) + c0) = make_float2(a1.x, a1.y);
        *(float2*)(xr + ((unsigned)(n0 + nb + 2) << 7) + c0) = make_float2(a2.x, a2.y);
        *(float2*)(xr + ((unsigned)(n0 + nb + 3) << 7) + c0) = make_float2(a3.x, a3.y);
    }
}

// ---------------- per-layer linear: h1 -> xl (fp16), xr (fp32); 8 nodes/block ------
__global__ void lin_kernel(const float* __restrict__ f,
                           const float* __restrict__ wlt, const float* __restrict__ bl,
                           const float* __restrict__ wrt, const float* __restrict__ br,
                           __half2* __restrict__ xl, float* __restrict__ xr) {
    int tid = threadIdx.x;
    int n0 = blockIdx.x * 8;
    __shared__ float se[8][HIDD];
    se[tid >> 5][tid & 31] = f[((unsigned)(n0 + (tid >> 5)) << 5) + (tid & 31)];
    __syncthreads();
    int mat = tid >> 7, grp = (tid >> 6) & 1, pr = tid & 63;
    int c0 = 2 * pr;
    const float* WT = mat ? wrt : wlt;
    const float* b  = mat ? br : bl;
    v2f bv2 = (v2f){b[c0], b[c0 + 1]};
    v2f a0 = bv2, a1 = bv2, a2 = bv2, a3 = bv2;
    int nb = grp * 4;
    #pragma unroll
    for (int k = 0; k < HIDD; k++) {
        v2f wk = *(const v2f*)(WT + k * HC + c0);
        a0 += wk * se[nb + 0][k]; a1 += wk * se[nb + 1][k];
        a2 += wk * se[nb + 2][k]; a3 += wk * se[nb + 3][k];
    }
    if (mat == 0) {
        xl[((unsigned)(n0 + nb + 0) << 6) + pr] = __floats2half2_rn(a0.x, a0.y);
        xl[((unsigned)(n0 + nb + 1) << 6) + pr] = __floats2half2_rn(a1.x, a1.y);
        xl[((unsigned)(n0 + nb + 2) << 6) + pr] = __floats2half2_rn(a2.x, a2.y);
        xl[((unsigned)(n0 + nb + 3) << 6) + pr] = __floats2half2_rn(a3.x, a3.y);
    } else {
        *(float2*)(xr + ((unsigned)(n0 + nb + 0) << 7) + c0) = make_float2(a0.x, a0.y);
        *(float2*)(xr + ((unsigned)(n0 + nb + 1) << 7) + c0) = make_float2(a1.x, a1.y);
        *(float2*)(xr + ((unsigned)(n0 + nb + 2) << 7) + c0) = make_float2(a2.x, a2.y);
        *(float2*)(xr + ((unsigned)(n0 + nb + 3) << 7) + c0) = make_float2(a3.x, a3.y);
    }
}

// ---------------- fused: edge scoring + softmax + aggregate + self-loop -------------
// one wave per dst node; lane owns channels (2*lane, 2*lane+1); head = lane>>4
// Logits are O(1) by construction -> plain exp2 softmax (shift-invariant, exact).
template<bool OUTHEAD>
__global__ void gat_fused_kernel(const __half2* __restrict__ xl, const float* __restrict__ xr,
                                 const float* __restrict__ eattr,
                                 const float* __restrict__ We, const float* __restrict__ att,
                                 const int* __restrict__ rowstart, const int2* __restrict__ csr_es,
                                 const float* __restrict__ bias,
                                 const float* __restrict__ Wout, const float* __restrict__ bout,
                                 float* __restrict__ out) {
    int n = (blockIdx.x * blockDim.x + threadIdx.x) >> 6;
    int lane = threadIdx.x & 63;
    if (n >= NN) return;
    n = __builtin_amdgcn_readfirstlane(n);
    int start = __builtin_amdgcn_readfirstlane(rowstart[n]);
    int end   = __builtin_amdgcn_readfirstlane(rowstart[n + 1]);
    int deg = end - start;
    int c0 = 2 * lane;

    v2f xrv = *(const v2f*)(xr + ((unsigned)n << 7) + c0);
    v2f attv = *(const v2f*)(att + c0) * LOG2E;
    v2f wv[16];
    {
        const float* ra = We + c0 * EDD;
        const float* rb = ra + EDD;
        float4 a0 = *(const float4*)(ra),     a1 = *(const float4*)(ra + 4);
        float4 a2 = *(const float4*)(ra + 8), a3 = *(const float4*)(ra + 12);
        float4 b0 = *(const float4*)(rb),     b1 = *(const float4*)(rb + 4);
        float4 b2 = *(const float4*)(rb + 8), b3 = *(const float4*)(rb + 12);
        wv[0]=(v2f){a0.x,b0.x}; wv[1]=(v2f){a0.y,b0.y}; wv[2]=(v2f){a0.z,b0.z}; wv[3]=(v2f){a0.w,b0.w};
        wv[4]=(v2f){a1.x,b1.x}; wv[5]=(v2f){a1.y,b1.y}; wv[6]=(v2f){a1.z,b1.z}; wv[7]=(v2f){a1.w,b1.w};
        wv[8]=(v2f){a2.x,b2.x}; wv[9]=(v2f){a2.y,b2.y}; wv[10]=(v2f){a2.z,b2.z}; wv[11]=(v2f){a2.w,b2.w};
        wv[12]=(v2f){a3.x,b3.x}; wv[13]=(v2f){a3.y,b3.y}; wv[14]=(v2f){a3.z,b3.z}; wv[15]=(v2f){a3.w,b3.w};
    }

    float lh = 0.f;
    v2f acc   = (v2f){0.f, 0.f};
    v2f easum = (v2f){0.f, 0.f};

    auto load_edge = [&](int i) -> Edge {
        int2 es = csr_es[i];
        int s = __builtin_amdgcn_readfirstlane(es.y);
        int e = __builtin_amdgcn_readfirstlane(es.x);
        Edge r;
        float2 xf = __half22float2(xl[((unsigned)s << 6) + lane]);
        r.x = (v2f){xf.x, xf.y};
        const float4* ep = (const float4*)(eattr + ((size_t)(unsigned)e << 4));
        float4 q0 = ep[0], q1 = ep[1], q2 = ep[2], q3 = ep[3];
        r.ea = wv[0]*q0.x + wv[1]*q0.y + wv[2]*q0.z  + wv[3]*q0.w
             + wv[4]*q1.x + wv[5]*q1.y + wv[6]*q1.z  + wv[7]*q1.w
             + wv[8]*q2.x + wv[9]*q2.y + wv[10]*q2.z + wv[11]*q2.w
             + wv[12]*q3.x+ wv[13]*q3.y+ wv[14]*q3.z + wv[15]*q3.w;
        return r;
    };

    auto proc_edge = [&](const Edge& E) {
        easum += E.ea;
        v2f z  = E.x + xrv + E.ea;
        v2f mm = lrelu2(z);
        v2f pp = mm * attv;
        float p = pp.x + pp.y;
        p += __shfl_xor(p, 1); p += __shfl_xor(p, 2);
        p += __shfl_xor(p, 4); p += __shfl_xor(p, 8);
        float w = exp2f(p);
        lh  += w;
        acc += E.x * w;
    };

    int i = start;
    int nfull = deg >> 2;
    if (nfull > 0) {
        Edge A0 = load_edge(i), A1 = load_edge(i + 1), A2 = load_edge(i + 2), A3 = load_edge(i + 3);
        for (int c = 1; c < nfull; c++) {
            Edge B0 = load_edge(i + 4), B1 = load_edge(i + 5),
                 B2 = load_edge(i + 6), B3 = load_edge(i + 7);
            proc_edge(A0); proc_edge(A1); proc_edge(A2); proc_edge(A3);
            A0 = B0; A1 = B1; A2 = B2; A3 = B3;
            i += 4;
        }
        proc_edge(A0); proc_edge(A1); proc_edge(A2); proc_edge(A3);
        i += 4;
    }
    int rem = end - i;
    if (rem > 0) {
        Edge T0 = load_edge(i), T1, T2;
        T1.x = T1.ea = T2.x = T2.ea = (v2f){0.f, 0.f};
        if (rem > 1) T1 = load_edge(i + 1);
        if (rem > 2) T2 = load_edge(i + 2);
        proc_edge(T0);
        if (rem > 1) proc_edge(T1);
        if (rem > 2) proc_edge(T2);
    }

    // self-loop: We @ mean(eattr) == mean(We @ eattr); src = n
    {
        float invdeg = 1.0f / (float)(deg > 0 ? deg : 1);
        Edge L;
        float2 xf = __half22float2(xl[((unsigned)n << 6) + lane]);
        L.x = (v2f){xf.x, xf.y};
        L.ea = easum * invdeg;
        proc_edge(L);
    }

    float inv = 1.0f / lh;
    float acc0 = acc.x * inv, acc1 = acc.y * inv;
    acc0 += __shfl_xor(acc0, 16); acc0 += __shfl_xor(acc0, 32);
    acc1 += __shfl_xor(acc1, 16); acc1 += __shfl_xor(acc1, 32);

    if (!OUTHEAD) {
        if (lane < 16) {
            float2 o = make_float2(acc0 * 0.25f + bias[2 * lane],
                                   acc1 * 0.25f + bias[2 * lane + 1]);
            *(float2*)(out + ((unsigned)n << 5) + 2 * lane) = o;
        }
    } else {
        __shared__ float sh[4][HIDD];
        int w = threadIdx.x >> 6;
        if (lane < 16) {
            sh[w][2 * lane]     = acc0 * 0.25f + bias[2 * lane];
            sh[w][2 * lane + 1] = acc1 * 0.25f + bias[2 * lane + 1];
        }
        float a = bout[lane];
        const float* wr = Wout + lane * HIDD;
        #pragma unroll
        for (int k = 0; k < HIDD; k++) a += sh[w][k] * wr[k];
        out[((unsigned)n << 6) + lane] = lrelu(a);
    }
}

extern "C" void kernel_launch(void* const* d_in, const int* in_sizes, int n_in,
                              void* d_out, int out_size, void* d_ws, size_t ws_size,
                              hipStream_t stream) {
    const float* x     = (const float*)d_in[0];
    const int*   ei    = (const int*)  d_in[1];
    const float* eattr = (const float*)d_in[2];
    const float* W0    = (const float*)d_in[3];
    const float* b0    = (const float*)d_in[4];
    const float* bn_g  = (const float*)d_in[5];
    const float* bn_b  = (const float*)d_in[6];
    const float* bn_m  = (const float*)d_in[7];
    const float* bn_v  = (const float*)d_in[8];
    const float* Wl[2]   = { (const float*)d_in[9],  (const float*)d_in[16] };
    const float* bl[2]   = { (const float*)d_in[10], (const float*)d_in[17] };
    const float* Wr[2]   = { (const float*)d_in[11], (const float*)d_in[18] };
    const float* br[2]   = { (const float*)d_in[12], (const float*)d_in[19] };
    const float* We[2]   = { (const float*)d_in[13], (const float*)d_in[20] };
    const float* att[2]  = { (const float*)d_in[14], (const float*)d_in[21] };
    const float* bias[2] = { (const float*)d_in[15], (const float*)d_in[22] };
    const float* Wout  = (const float*)d_in[23];
    const float* bout  = (const float*)d_in[24];
    float* out = (float*)d_out;

    const int NB = (NN + 1023) / 1024;   // 49 scan blocks
    char* p = (char*)d_ws;
    auto carve = [&](size_t bytes) { char* r = p; p += (bytes + 255) & ~(size_t)255; return r; };
    float*   h1       = (float*)  carve((size_t)NN * HIDD * 4);
    __half2* xl       = (__half2*)carve((size_t)NN * HC * 2);
    float*   xr       = (float*)  carve((size_t)NN * HC * 4);
    int*     cnt      = (int*)    carve((size_t)NN * 4);
    int*     rank     = (int*)    carve((size_t)EE * 4);
    int*     pre      = (int*)    carve((size_t)NN * 4);
    int*     bsum     = (int*)    carve((size_t)64 * 4);
    int*     rowstart = (int*)    carve((size_t)(NN + 1) * 4);
    int2*    csr_es   = (int2*)   carve((size_t)EE * 8);
    float*   w0t      = (float*)  carve((size_t)IND * HIDD * 4);
    float*   b0f      = (float*)  carve((size_t)HIDD * 4);
    float*   wlt0     = (float*)  carve((size_t)HIDD * HC * 4);
    float*   wrt0     = (float*)  carve((size_t)HIDD * HC * 4);
    float*   wlt1     = (float*)  carve((size_t)HIDD * HC * 4);
    float*   wrt1     = (float*)  carve((size_t)HIDD * HC * 4);

    hipMemsetAsync(cnt, 0, (size_t)NN * 4, stream);

    count_fold_kernel<<<EE / 256 + 1, 256, 0, stream>>>(
        ei, cnt, rank, W0, b0, bn_g, bn_b, bn_m, bn_v,
        Wl[0], Wr[0], Wl[1], Wr[1], w0t, b0f, wlt0, wrt0, wlt1, wrt1);
    scan1_kernel<<<NB, 1024, 0, stream>>>(cnt, pre, bsum);
    scan3_kernel<<<NB, 1024, 0, stream>>>(rowstart, pre, bsum, NB);
    scatter_kernel<<<(EE + 255) / 256, 256, 0, stream>>>(ei, rowstart, rank, csr_es);

    embed_lin_kernel<<<NN / 8, 256, 0, stream>>>(x, w0t, b0f, wlt0, bl[0], wrt0, br[0], xl, xr);
    gat_fused_kernel<false><<<(NN * 64) / 256, 256, 0, stream>>>(
        xl, xr, eattr, We[0], att[0], rowstart, csr_es, bias[0], nullptr, nullptr, h1);

    lin_kernel<<<NN / 8, 256, 0, stream>>>(h1, wlt1, bl[1], wrt1, br[1], xl, xr);
    gat_fused_kernel<true><<<(NN * 64) / 256, 256, 0, stream>>>(
        xl, xr, eattr, We[1], att[1], rowstart, csr_es, bias[1], Wout, bout, out);
}

// Round 9
// 575.868 us; speedup vs baseline: 1.2704x; 1.0439x over previous
//
#include <hip/hip_runtime.h>
#include <hip/hip_fp16.h>
#include <math.h>

#define NN   50000
#define EE   800000
#define IND  128
#define EDD  16
#define HIDD 32
#define NH   4
#define HC   128     // NH*HIDD
#define OUTD 64
#define NEG  0.1f
#define BN_EPS 1e-5f
#define LOG2E 1.44269504088896340736f

typedef __attribute__((ext_vector_type(2))) float v2f;

__device__ __forceinline__ float lrelu(float x) { return fmaxf(x, NEG * x); }
__device__ __forceinline__ v2f lrelu2(v2f v) { return __builtin_elementwise_max(v, v * NEG); }
__device__ __forceinline__ float2 unpk(float f) {
    return __half22float2(__builtin_bit_cast(__half2, f));
}

// ---------------- count (+rank) and weight fold/transpose in one grid -------------
__global__ void count_fold_kernel(const int* __restrict__ ei, int* __restrict__ cnt,
                                  int* __restrict__ rank,
                                  const float* __restrict__ W0, const float* __restrict__ b0,
                                  const float* __restrict__ g, const float* __restrict__ bb,
                                  const float* __restrict__ bm, const float* __restrict__ bv,
                                  const float* __restrict__ Wl0, const float* __restrict__ Wr0,
                                  const float* __restrict__ Wl1, const float* __restrict__ Wr1,
                                  float* __restrict__ w0t, float* __restrict__ b0f,
                                  float* __restrict__ wlt0, float* __restrict__ wrt0,
                                  float* __restrict__ wlt1, float* __restrict__ wrt1) {
    if (blockIdx.x < EE / 256) {
        int e = blockIdx.x * 256 + threadIdx.x;
        rank[e] = atomicAdd(&cnt[ei[EE + e]], 1);
        return;
    }
    int tid = threadIdx.x;
    for (int idx = tid; idx < IND * HIDD; idx += 256) {
        int k = idx >> 5, c = idx & 31;
        float s = g[c] * (1.0f / sqrtf(bv[c] + BN_EPS));
        w0t[idx] = W0[c * IND + k] * s;
    }
    if (tid < HIDD) {
        float s = g[tid] * (1.0f / sqrtf(bv[tid] + BN_EPS));
        b0f[tid] = (b0[tid] - bm[tid]) * s + bb[tid];
    }
    for (int idx = tid; idx < HIDD * HC; idx += 256) {
        int k = idx >> 7, c = idx & 127;
        wlt0[idx] = Wl0[c * HIDD + k];
        wrt0[idx] = Wr0[c * HIDD + k];
        wlt1[idx] = Wl1[c * HIDD + k];
        wrt1[idx] = Wr1[c * HIDD + k];
    }
}

// parallel exclusive scan of cnt[NN] -> rowstart[NN+1]
__global__ void scan1_kernel(const int* cnt, int* pre, int* bsum) {
    int i = blockIdx.x * 1024 + threadIdx.x;
    int lane = threadIdx.x & 63, wid = threadIdx.x >> 6;
    __shared__ int wsum[16];
    int v = (i < NN) ? cnt[i] : 0;
    int s = v;
    #pragma unroll
    for (int off = 1; off < 64; off <<= 1) {
        int t = __shfl_up(s, off);
        if (lane >= off) s += t;
    }
    if (lane == 63) wsum[wid] = s;
    __syncthreads();
    if (wid == 0) {
        int ws = (lane < 16) ? wsum[lane] : 0;
        #pragma unroll
        for (int off = 1; off < 16; off <<= 1) {
            int t = __shfl_up(ws, off);
            if (lane >= off) ws += t;
        }
        if (lane < 16) wsum[lane] = ws;
    }
    __syncthreads();
    int woff = (wid > 0) ? wsum[wid - 1] : 0;
    if (i < NN) pre[i] = woff + s - v;
    if (threadIdx.x == 1023) bsum[blockIdx.x] = wsum[15];
}

__global__ void scan3_kernel(int* rowstart, const int* pre, const int* bsum, int nb) {
    __shared__ int boff_s;
    if (threadIdx.x < 64) {
        int lane = threadIdx.x;
        int v = (lane < nb) ? bsum[lane] : 0;
        int s = v;
        #pragma unroll
        for (int off = 1; off < 64; off <<= 1) {
            int t = __shfl_up(s, off);
            if (lane >= off) s += t;
        }
        if (lane == (int)blockIdx.x) boff_s = s - v;
    }
    __syncthreads();
    int i = blockIdx.x * 1024 + threadIdx.x;
    if (i < NN) rowstart[i] = pre[i] + boff_s;
    if (i == 0) rowstart[NN] = EE;
}

// atomic-free scatter; also reorders edge_attr into CSR order as fp16
__global__ void scatter_kernel(const int* __restrict__ ei, const int* __restrict__ rowstart,
                               const int* __restrict__ rank, const float* __restrict__ eattr,
                               int* __restrict__ csr_src, __half2* __restrict__ ea16) {
    int e = blockIdx.x * blockDim.x + threadIdx.x;
    if (e >= EE) return;
    int d = ei[EE + e];
    int pos = rowstart[d] + rank[e];
    csr_src[pos] = ei[e];
    const float4* src = (const float4*)(eattr + ((size_t)e << 4));
    float4 q0 = src[0], q1 = src[1], q2 = src[2], q3 = src[3];
    __half2 h[8];
    h[0] = __floats2half2_rn(q0.x, q0.y); h[1] = __floats2half2_rn(q0.z, q0.w);
    h[2] = __floats2half2_rn(q1.x, q1.y); h[3] = __floats2half2_rn(q1.z, q1.w);
    h[4] = __floats2half2_rn(q2.x, q2.y); h[5] = __floats2half2_rn(q2.z, q2.w);
    h[6] = __floats2half2_rn(q3.x, q3.y); h[7] = __floats2half2_rn(q3.z, q3.w);
    float4* dst = (float4*)(ea16 + ((size_t)pos << 3));
    dst[0] = *(float4*)&h[0];
    dst[1] = *(float4*)&h[4];
}

// ---------------- fused embed + layer-0 linear: x -> xl (fp16), xr (fp32) ----------
__global__ void embed_lin_kernel(const float* __restrict__ x,
                                 const float* __restrict__ w0t, const float* __restrict__ b0f,
                                 const float* __restrict__ wlt, const float* __restrict__ bl,
                                 const float* __restrict__ wrt, const float* __restrict__ br,
                                 __half2* __restrict__ xl, float* __restrict__ xr) {
    int tid = threadIdx.x;
    int n0 = blockIdx.x * 8;
    __shared__ float sx[8 * IND];
    __shared__ float se[8][HIDD];
    *(float4*)(sx + tid * 4) = *(const float4*)(x + (size_t)n0 * IND + tid * 4);
    __syncthreads();
    {
        int r = tid >> 5, c = tid & 31;
        float acc = b0f[c];
        const float* xrow = sx + r * IND;
        #pragma unroll 8
        for (int k = 0; k < IND; k++) acc += xrow[k] * w0t[k * HIDD + c];
        se[r][c] = lrelu(acc);
    }
    __syncthreads();
    int mat = tid >> 7, grp = (tid >> 6) & 1, pr = tid & 63;
    int c0 = 2 * pr;
    const float* WT = mat ? wrt : wlt;
    const float* b  = mat ? br : bl;
    v2f bv2 = (v2f){b[c0], b[c0 + 1]};
    v2f a0 = bv2, a1 = bv2, a2 = bv2, a3 = bv2;
    int nb = grp * 4;
    #pragma unroll
    for (int k = 0; k < HIDD; k++) {
        v2f wk = *(const v2f*)(WT + k * HC + c0);
        a0 += wk * se[nb + 0][k]; a1 += wk * se[nb + 1][k];
        a2 += wk * se[nb + 2][k]; a3 += wk * se[nb + 3][k];
    }
    if (mat == 0) {
        xl[((unsigned)(n0 + nb + 0) << 6) + pr] = __floats2half2_rn(a0.x, a0.y);
        xl[((unsigned)(n0 + nb + 1) << 6) + pr] = __floats2half2_rn(a1.x, a1.y);
        xl[((unsigned)(n0 + nb + 2) << 6) + pr] = __floats2half2_rn(a2.x, a2.y);
        xl[((unsigned)(n0 + nb + 3) << 6) + pr] = __floats2half2_rn(a3.x, a3.y);
    } else {
        *(float2*)(xr + ((unsigned)(n0 + nb + 0) << 7) + c0) = make_float2(a0.x, a0.y);
        *(float2*)(xr + ((unsigned)(n0 + nb + 1) << 7) + c0) = make_float2(a1.x, a1.y);
        *(float2*)(xr + ((unsigned)(n0 + nb + 2) << 7) + c0) = make_float2(a2.x, a2.y);
        *(float2*)(xr + ((unsigned)(n0 + nb + 3) << 7) + c0) = make_float2(a3.x, a3.y);
    }
}

// ---------------- per-layer linear: h1 -> xl (fp16), xr (fp32); 8 nodes/block ------
__global__ void lin_kernel(const float* __restrict__ f,
                           const float* __restrict__ wlt, const float* __restrict__ bl,
                           const float* __restrict__ wrt, const float* __restrict__ br,
                           __half2* __restrict__ xl, float* __restrict__ xr) {
    int tid = threadIdx.x;
    int n0 = blockIdx.x * 8;
    __shared__ float se[8][HIDD];
    se[tid >> 5][tid & 31] = f[((unsigned)(n0 + (tid >> 5)) << 5) + (tid & 31)];
    __syncthreads();
    int mat = tid >> 7, grp = (tid >> 6) & 1, pr = tid & 63;
    int c0 = 2 * pr;
    const float* WT = mat ? wrt : wlt;
    const float* b  = mat ? br : bl;
    v2f bv2 = (v2f){b[c0], b[c0 + 1]};
    v2f a0 = bv2, a1 = bv2, a2 = bv2, a3 = bv2;
    int nb = grp * 4;
    #pragma unroll
    for (int k = 0; k < HIDD; k++) {
        v2f wk = *(const v2f*)(WT + k * HC + c0);
        a0 += wk * se[nb + 0][k]; a1 += wk * se[nb + 1][k];
        a2 += wk * se[nb + 2][k]; a3 += wk * se[nb + 3][k];
    }
    if (mat == 0) {
        xl[((unsigned)(n0 + nb + 0) << 6) + pr] = __floats2half2_rn(a0.x, a0.y);
        xl[((unsigned)(n0 + nb + 1) << 6) + pr] = __floats2half2_rn(a1.x, a1.y);
        xl[((unsigned)(n0 + nb + 2) << 6) + pr] = __floats2half2_rn(a2.x, a2.y);
        xl[((unsigned)(n0 + nb + 3) << 6) + pr] = __floats2half2_rn(a3.x, a3.y);
    } else {
        *(float2*)(xr + ((unsigned)(n0 + nb + 0) << 7) + c0) = make_float2(a0.x, a0.y);
        *(float2*)(xr + ((unsigned)(n0 + nb + 1) << 7) + c0) = make_float2(a1.x, a1.y);
        *(float2*)(xr + ((unsigned)(n0 + nb + 2) << 7) + c0) = make_float2(a2.x, a2.y);
        *(float2*)(xr + ((unsigned)(n0 + nb + 3) << 7) + c0) = make_float2(a3.x, a3.y);
    }
}

// ---------------- fused: edge scoring + softmax + aggregate + self-loop -------------
// one wave per dst node; lane owns channels (2*lane, 2*lane+1); head = lane>>4
// csr_src: 4B/edge; ea16: fp16 edge_attr in CSR order (sequential, index-derived addr)
template<bool OUTHEAD>
__global__ void gat_fused_kernel(const __half2* __restrict__ xl, const float* __restrict__ xr,
                                 const __half2* __restrict__ ea16,
                                 const float* __restrict__ We, const float* __restrict__ att,
                                 const int* __restrict__ rowstart, const int* __restrict__ csr_src,
                                 const float* __restrict__ bias,
                                 const float* __restrict__ Wout, const float* __restrict__ bout,
                                 float* __restrict__ out) {
    int n = (blockIdx.x * blockDim.x + threadIdx.x) >> 6;
    int lane = threadIdx.x & 63;
    if (n >= NN) return;
    n = __builtin_amdgcn_readfirstlane(n);
    int start = __builtin_amdgcn_readfirstlane(rowstart[n]);
    int end   = __builtin_amdgcn_readfirstlane(rowstart[n + 1]);
    int deg = end - start;
    int c0 = 2 * lane;

    // prefetch self-loop x row early (waited at the very end)
    __half2 xLh = xl[((unsigned)n << 6) + lane];
    v2f xrv = *(const v2f*)(xr + ((unsigned)n << 7) + c0);
    v2f attv = *(const v2f*)(att + c0) * LOG2E;
    v2f wv[16];
    {
        const float* ra = We + c0 * EDD;
        const float* rb = ra + EDD;
        float4 a0 = *(const float4*)(ra),     a1 = *(const float4*)(ra + 4);
        float4 a2 = *(const float4*)(ra + 8), a3 = *(const float4*)(ra + 12);
        float4 b0 = *(const float4*)(rb),     b1 = *(const float4*)(rb + 4);
        float4 b2 = *(const float4*)(rb + 8), b3 = *(const float4*)(rb + 12);
        wv[0]=(v2f){a0.x,b0.x}; wv[1]=(v2f){a0.y,b0.y}; wv[2]=(v2f){a0.z,b0.z}; wv[3]=(v2f){a0.w,b0.w};
        wv[4]=(v2f){a1.x,b1.x}; wv[5]=(v2f){a1.y,b1.y}; wv[6]=(v2f){a1.z,b1.z}; wv[7]=(v2f){a1.w,b1.w};
        wv[8]=(v2f){a2.x,b2.x}; wv[9]=(v2f){a2.y,b2.y}; wv[10]=(v2f){a2.z,b2.z}; wv[11]=(v2f){a2.w,b2.w};
        wv[12]=(v2f){a3.x,b3.x}; wv[13]=(v2f){a3.y,b3.y}; wv[14]=(v2f){a3.z,b3.z}; wv[15]=(v2f){a3.w,b3.w};
    }

    float lh = 0.f;
    v2f acc   = (v2f){0.f, 0.f};
    v2f easum = (v2f){0.f, 0.f};

    // project 16 fp16 edge-attr values (as 2 float4 raws) through We columns
    auto proj = [&](float4 r0, float4 r1) -> v2f {
        float2 t0 = unpk(r0.x), t1 = unpk(r0.y), t2 = unpk(r0.z), t3 = unpk(r0.w);
        float2 t4 = unpk(r1.x), t5 = unpk(r1.y), t6 = unpk(r1.z), t7 = unpk(r1.w);
        return wv[0]*t0.x  + wv[1]*t0.y  + wv[2]*t1.x  + wv[3]*t1.y
             + wv[4]*t2.x  + wv[5]*t2.y  + wv[6]*t3.x  + wv[7]*t3.y
             + wv[8]*t4.x  + wv[9]*t4.y  + wv[10]*t5.x + wv[11]*t5.y
             + wv[12]*t6.x + wv[13]*t6.y + wv[14]*t7.x + wv[15]*t7.y;
    };

    auto proc = [&](v2f xv, v2f ea) {
        easum += ea;
        v2f z  = xv + xrv + ea;
        v2f mm = lrelu2(z);
        v2f pp = mm * attv;
        float p = pp.x + pp.y;
        p += __shfl_xor(p, 1); p += __shfl_xor(p, 2);
        p += __shfl_xor(p, 4); p += __shfl_xor(p, 8);
        float w = exp2f(p);
        lh  += w;
        acc += xv * w;
    };

    // GATHER: x gathers (dep on idx) + ea loads (index-derived, no dependency) + project
    #define GATHER(i0, S0, S1, S2, S3, X0, X1, X2, X3, E0, E1, E2, E3) do {           \
        __half2 xh0 = xl[((unsigned)(S0) << 6) + lane];                                \
        __half2 xh1 = xl[((unsigned)(S1) << 6) + lane];                                \
        __half2 xh2 = xl[((unsigned)(S2) << 6) + lane];                                \
        __half2 xh3 = xl[((unsigned)(S3) << 6) + lane];                                \
        const float4* ep = (const float4*)(ea16 + ((size_t)(unsigned)(i0) << 3));      \
        float4 r00 = ep[0], r01 = ep[1], r10 = ep[2], r11 = ep[3];                     \
        float4 r20 = ep[4], r21 = ep[5], r30 = ep[6], r31 = ep[7];                     \
        E0 = proj(r00, r01); E1 = proj(r10, r11);                                      \
        E2 = proj(r20, r21); E3 = proj(r30, r31);                                      \
        float2 xf;                                                                     \
        xf = __half22float2(xh0); X0 = (v2f){xf.x, xf.y};                              \
        xf = __half22float2(xh1); X1 = (v2f){xf.x, xf.y};                              \
        xf = __half22float2(xh2); X2 = (v2f){xf.x, xf.y};                              \
        xf = __half22float2(xh3); X3 = (v2f){xf.x, xf.y};                              \
    } while (0)

    int i = start;
    int nf = deg >> 2;
    if (nf > 0) {
        // idx VGPR prefetch one chunk ahead (clamped, branch-free)
        int v0 = csr_src[i],     v1 = csr_src[i + 1],
            v2 = csr_src[i + 2], v3 = csr_src[i + 3];
        int j4 = (i + 4 > EE - 4) ? (EE - 4) : (i + 4);
        int u0 = csr_src[j4],     u1 = csr_src[j4 + 1],
            u2 = csr_src[j4 + 2], u3 = csr_src[j4 + 3];
        int s0 = __builtin_amdgcn_readfirstlane(v0), s1 = __builtin_amdgcn_readfirstlane(v1);
        int s2 = __builtin_amdgcn_readfirstlane(v2), s3 = __builtin_amdgcn_readfirstlane(v3);
        v2f A0x, A1x, A2x, A3x, A0e, A1e, A2e, A3e;
        GATHER(i, s0, s1, s2, s3, A0x, A1x, A2x, A3x, A0e, A1e, A2e, A3e);
        for (int k = 1; k < nf; k++) {
            int jn = i + 4 * (k + 1);
            jn = (jn > EE - 4) ? (EE - 4) : jn;
            int w0 = csr_src[jn],     w1 = csr_src[jn + 1],
                w2 = csr_src[jn + 2], w3 = csr_src[jn + 3];
            int t0 = __builtin_amdgcn_readfirstlane(u0), t1 = __builtin_amdgcn_readfirstlane(u1);
            int t2 = __builtin_amdgcn_readfirstlane(u2), t3 = __builtin_amdgcn_readfirstlane(u3);
            v2f B0x, B1x, B2x, B3x, B0e, B1e, B2e, B3e;
            GATHER(i + 4 * k, t0, t1, t2, t3, B0x, B1x, B2x, B3x, B0e, B1e, B2e, B3e);
            proc(A0x, A0e); proc(A1x, A1e); proc(A2x, A2e); proc(A3x, A3e);
            A0x = B0x; A1x = B1x; A2x = B2x; A3x = B3x;
            A0e = B0e; A1e = B1e; A2e = B2e; A3e = B3e;
            u0 = w0; u1 = w1; u2 = w2; u3 = w3;
        }
        proc(A0x, A0e); proc(A1x, A1e); proc(A2x, A2e); proc(A3x, A3e);
        i += 4 * nf;
    }
    // tail (<=3): issue all loads, then process
    int rem = end - i;
    if (rem > 0) {
        v2f Tx[3], Te[3];
        int sA = __builtin_amdgcn_readfirstlane(csr_src[i]);
        int sB = (rem > 1) ? __builtin_amdgcn_readfirstlane(csr_src[i + 1]) : sA;
        int sC = (rem > 2) ? __builtin_amdgcn_readfirstlane(csr_src[i + 2]) : sA;
        __half2 xh0 = xl[((unsigned)sA << 6) + lane];
        __half2 xh1 = xl[((unsigned)sB << 6) + lane];
        __half2 xh2 = xl[((unsigned)sC << 6) + lane];
        const float4* ep = (const float4*)(ea16 + ((size_t)(unsigned)i << 3));
        int lim2 = (rem > 1) ? 2 : 0, lim4 = (rem > 2) ? 4 : 0;
        float4 r00 = ep[0], r01 = ep[1];
        float4 r10 = ep[lim2], r11 = ep[lim2 + 1];
        float4 r20 = ep[lim4], r21 = ep[lim4 + 1];
        float2 xf;
        xf = __half22float2(xh0); Tx[0] = (v2f){xf.x, xf.y};
        xf = __half22float2(xh1); Tx[1] = (v2f){xf.x, xf.y};
        xf = __half22float2(xh2); Tx[2] = (v2f){xf.x, xf.y};
        Te[0] = proj(r00, r01); Te[1] = proj(r10, r11); Te[2] = proj(r20, r21);
        proc(Tx[0], Te[0]);
        if (rem > 1) proc(Tx[1], Te[1]);
        if (rem > 2) proc(Tx[2], Te[2]);
    }

    // self-loop: We @ mean(eattr) == mean(We @ eattr); src = n
    {
        float invdeg = 1.0f / (float)(deg > 0 ? deg : 1);
        float2 xf = __half22float2(xLh);
        proc((v2f){xf.x, xf.y}, easum * invdeg);
    }

    float inv = 1.0f / lh;
    float acc0 = acc.x * inv, acc1 = acc.y * inv;
    acc0 += __shfl_xor(acc0, 16); acc0 += __shfl_xor(acc0, 32);
    acc1 += __shfl_xor(acc1, 16); acc1 += __shfl_xor(acc1, 32);

    if (!OUTHEAD) {
        if (lane < 16) {
            float2 o = make_float2(acc0 * 0.25f + bias[2 * lane],
                                   acc1 * 0.25f + bias[2 * lane + 1]);
            *(float2*)(out + ((unsigned)n << 5) + 2 * lane) = o;
        }
    } else {
        __shared__ float sh[4][HIDD];
        int w = threadIdx.x >> 6;
        if (lane < 16) {
            sh[w][2 * lane]     = acc0 * 0.25f + bias[2 * lane];
            sh[w][2 * lane + 1] = acc1 * 0.25f + bias[2 * lane + 1];
        }
        float a = bout[lane];
        const float* wr = Wout + lane * HIDD;
        #pragma unroll
        for (int k = 0; k < HIDD; k++) a += sh[w][k] * wr[k];
        out[((unsigned)n << 6) + lane] = lrelu(a);
    }
    #undef GATHER
}

extern "C" void kernel_launch(void* const* d_in, const int* in_sizes, int n_in,
                              void* d_out, int out_size, void* d_ws, size_t ws_size,
                              hipStream_t stream) {
    const float* x     = (const float*)d_in[0];
    const int*   ei    = (const int*)  d_in[1];
    const float* eattr = (const float*)d_in[2];
    const float* W0    = (const float*)d_in[3];
    const float* b0    = (const float*)d_in[4];
    const float* bn_g  = (const float*)d_in[5];
    const float* bn_b  = (const float*)d_in[6];
    const float* bn_m  = (const float*)d_in[7];
    const float* bn_v  = (const float*)d_in[8];
    const float* Wl[2]   = { (const float*)d_in[9],  (const float*)d_in[16] };
    const float* bl[2]   = { (const float*)d_in[10], (const float*)d_in[17] };
    const float* Wr[2]   = { (const float*)d_in[11], (const float*)d_in[18] };
    const float* br[2]   = { (const float*)d_in[12], (const float*)d_in[19] };
    const float* We[2]   = { (const float*)d_in[13], (const float*)d_in[20] };
    const float* att[2]  = { (const float*)d_in[14], (const float*)d_in[21] };
    const float* bias[2] = { (const float*)d_in[15], (const float*)d_in[22] };
    const float* Wout  = (const float*)d_in[23];
    const float* bout  = (const float*)d_in[24];
    float* out = (float*)d_out;

    const int NB = (NN + 1023) / 1024;
    char* p = (char*)d_ws;
    auto carve = [&](size_t bytes) { char* r = p; p += (bytes + 255) & ~(size_t)255; return r; };
    float*   h1       = (float*)  carve((size_t)NN * HIDD * 4);
    __half2* xl       = (__half2*)carve((size_t)NN * HC * 2);
    float*   xr       = (float*)  carve((size_t)NN * HC * 4);
    int*     cnt      = (int*)    carve((size_t)NN * 4);
    int*     rank     = (int*)    carve((size_t)EE * 4);
    int*     pre      = (int*)    carve((size_t)NN * 4);
    int*     bsum     = (int*)    carve((size_t)64 * 4);
    int*     rowstart = (int*)    carve((size_t)(NN + 1) * 4);
    int*     csr_src  = (int*)    carve((size_t)EE * 4);
    __half2* ea16     = (__half2*)carve((size_t)EE * EDD * 2);
    float*   w0t      = (float*)  carve((size_t)IND * HIDD * 4);
    float*   b0f      = (float*)  carve((size_t)HIDD * 4);
    float*   wlt0     = (float*)  carve((size_t)HIDD * HC * 4);
    float*   wrt0     = (float*)  carve((size_t)HIDD * HC * 4);
    float*   wlt1     = (float*)  carve((size_t)HIDD * HC * 4);
    float*   wrt1     = (float*)  carve((size_t)HIDD * HC * 4);

    hipMemsetAsync(cnt, 0, (size_t)NN * 4, stream);

    count_fold_kernel<<<EE / 256 + 1, 256, 0, stream>>>(
        ei, cnt, rank, W0, b0, bn_g, bn_b, bn_m, bn_v,
        Wl[0], Wr[0], Wl[1], Wr[1], w0t, b0f, wlt0, wrt0, wlt1, wrt1);
    scan1_kernel<<<NB, 1024, 0, stream>>>(cnt, pre, bsum);
    scan3_kernel<<<NB, 1024, 0, stream>>>(rowstart, pre, bsum, NB);
    scatter_kernel<<<(EE + 255) / 256, 256, 0, stream>>>(ei, rowstart, rank, eattr,
                                                         csr_src, ea16);

    embed_lin_kernel<<<NN / 8, 256, 0, stream>>>(x, w0t, b0f, wlt0, bl[0], wrt0, br[0], xl, xr);
    gat_fused_kernel<false><<<(NN * 64) / 256, 256, 0, stream>>>(
        xl, xr, ea16, We[0], att[0], rowstart, csr_src, bias[0], nullptr, nullptr, h1);

    lin_kernel<<<NN / 8, 256, 0, stream>>>(h1, wlt1, bl[1], wrt1, br[1], xl, xr);
    gat_fused_kernel<true><<<(NN * 64) / 256, 256, 0, stream>>>(
        xl, xr, ea16, We[1], att[1], rowstart, csr_src, bias[1], Wout, bout, out);
}